// Round 1
// baseline (485.800 us; speedup 1.0000x reference)
//
#include <hip/hip_runtime.h>

#define NN 100000     // nodes
#define NE 1600000    // edges
#define D  64         // feature dim (in == out)
#define EPW 8         // edges per wave in scatter

// agg[i] = (1+eps) * x[i]  — scatter then adds neighbor sums on top.
__global__ void init_kernel(const float* __restrict__ x,
                            const float* __restrict__ eps,
                            float* __restrict__ agg) {
    int i = blockIdx.x * blockDim.x + threadIdx.x;
    float e = 1.0f + *eps;
    if (i < NN * D) agg[i] = e * x[i];
}

// One wave per EPW edges; lane = feature dim. Coalesced row read + coalesced
// atomicAdd into agg[dst].
__global__ void scatter_kernel(const float* __restrict__ x,
                               const int* __restrict__ ei,
                               float* __restrict__ agg) {
    const int lane   = threadIdx.x & 63;
    const int waveId = blockIdx.x * (blockDim.x >> 6) + (threadIdx.x >> 6);
    const int e0     = waveId * EPW;
    #pragma unroll
    for (int j = 0; j < EPW; ++j) {
        int e = e0 + j;
        if (e < NE) {
            int src = ei[e];        // edge_index[0][e]
            int dst = ei[NE + e];   // edge_index[1][e]
            atomicAdd(&agg[dst * D + lane], x[src * D + lane]);
        }
    }
}

// One wave per node (grid-stride). Lane d holds column d of W1 and W2 in
// registers (128 VGPRs); h[k] broadcast via v_readlane (VALU pipe, no LDS).
// out = relu(h@W1 + b1) @ W2 + b2
__global__ __launch_bounds__(256) void mlp_kernel(const float* __restrict__ h0,
                                                  const float* __restrict__ W1,
                                                  const float* __restrict__ b1,
                                                  const float* __restrict__ W2,
                                                  const float* __restrict__ b2,
                                                  float* __restrict__ out) {
    const int lane   = threadIdx.x & 63;
    const int wave   = blockIdx.x * (blockDim.x >> 6) + (threadIdx.x >> 6);
    const int nwaves = gridDim.x * (blockDim.x >> 6);

    float w1[D], w2[D];
    #pragma unroll
    for (int k = 0; k < D; ++k) {
        w1[k] = W1[k * D + lane];   // coalesced; cached after first block
        w2[k] = W2[k * D + lane];
    }
    const float bb1 = b1[lane];
    const float bb2 = b2[lane];

    for (int node = wave; node < NN; node += nwaves) {
        float hv = h0[node * D + lane];   // lane k holds h[node][k]
        float acc1 = bb1;
        #pragma unroll
        for (int k = 0; k < D; ++k) {
            float s = __int_as_float(__builtin_amdgcn_readlane(__float_as_int(hv), k));
            acc1 = fmaf(s, w1[k], acc1);
        }
        acc1 = fmaxf(acc1, 0.0f);         // relu; lane d holds h1[node][d]
        float acc2 = bb2;
        #pragma unroll
        for (int k = 0; k < D; ++k) {
            float s = __int_as_float(__builtin_amdgcn_readlane(__float_as_int(acc1), k));
            acc2 = fmaf(s, w2[k], acc2);
        }
        out[node * D + lane] = acc2;
    }
}

extern "C" void kernel_launch(void* const* d_in, const int* in_sizes, int n_in,
                              void* d_out, int out_size, void* d_ws, size_t ws_size,
                              hipStream_t stream) {
    const float* x   = (const float*)d_in[0];
    const int*   ei  = (const int*)d_in[1];
    const float* W1  = (const float*)d_in[2];
    const float* b1  = (const float*)d_in[3];
    const float* W2  = (const float*)d_in[4];
    const float* b2  = (const float*)d_in[5];
    const float* eps = (const float*)d_in[6];
    float*       out = (float*)d_out;
    float*       agg = (float*)d_ws;   // N*D floats = 25.6 MB scratch

    // agg = (1+eps)*x
    init_kernel<<<(NN * D + 255) / 256, 256, 0, stream>>>(x, eps, agg);

    // agg += segment_sum(x[src] -> dst)
    const int edges_per_block = EPW * (256 / 64);
    scatter_kernel<<<(NE + edges_per_block - 1) / edges_per_block, 256, 0, stream>>>(x, ei, agg);

    // out = relu(agg@W1+b1)@W2+b2
    mlp_kernel<<<1024, 256, 0, stream>>>(agg, W1, b1, W2, b2, out);
}